// Round 1
// baseline (2398.849 us; speedup 1.0000x reference)
//
#include <hip/hip_runtime.h>
#include <hip/hip_bf16.h>
#include <stdint.h>

#define B_ 32
#define L_ 128
#define H_ 512
#define E_ 256
#define V_ 32000
#define G4 2048   /* 4*H */

typedef __attribute__((ext_vector_type(8))) short short8;
typedef __attribute__((ext_vector_type(4))) float f32x4;

__device__ __forceinline__ short f2bf(float f){
  uint32_t u = __builtin_bit_cast(uint32_t, f);
  u += 0x7FFFu + ((u >> 16) & 1u);           // RNE
  return (short)(u >> 16);
}
__device__ __forceinline__ short8 ld8f_bf(const float* p){
  const f32x4* q = (const f32x4*)p;
  f32x4 a = q[0], b = q[1];
  short8 r;
  r[0]=f2bf(a[0]); r[1]=f2bf(a[1]); r[2]=f2bf(a[2]); r[3]=f2bf(a[3]);
  r[4]=f2bf(b[0]); r[5]=f2bf(b[1]); r[6]=f2bf(b[2]); r[7]=f2bf(b[3]);
  return r;
}
__device__ __forceinline__ f32x4 mfma16(short8 a, short8 b, f32x4 c){
  return __builtin_amdgcn_mfma_f32_16x16x32_bf16(a, b, c, 0, 0, 0);
}
__device__ __forceinline__ float sigm(float x){
  x = fminf(30.f, fmaxf(-30.f, x));
  return 1.f / (1.f + __expf(-x));
}
__device__ __forceinline__ float tanh_f(float x){
  x = fminf(15.f, fmaxf(-15.f, x));
  float e = __expf(-2.f * x);
  return (1.f - e) / (1.f + e);
}

// ---------------------------------------------------------------- init/cast
__global__ void k_init(const float* __restrict__ cnn,
    const float* __restrict__ w_hh1, const float* __restrict__ w_ih2,
    const float* __restrict__ w_hh2,
    short* __restrict__ wb1, short* __restrict__ wb2, short* __restrict__ wb3,
    float* __restrict__ c1, float* __restrict__ c2, short* __restrict__ h1b,
    float* __restrict__ row_sum)
{
  const int stride = gridDim.x * blockDim.x;
  const int tid0 = blockIdx.x * blockDim.x + threadIdx.x;
  for (int i = tid0; i < G4 * H_; i += stride){
    wb1[i] = f2bf(w_hh1[i]); wb2[i] = f2bf(w_ih2[i]); wb3[i] = f2bf(w_hh2[i]);
  }
  for (int i = tid0; i < B_ * H_; i += stride){
    c1[i] = cnn[i]; c2[i] = 0.f; h1b[i] = 0; h1b[B_ * H_ + i] = 0;
  }
  for (int i = tid0; i < B_ * L_; i += stride) row_sum[i] = 0.f;
}

// ------------------------------------------- xW1 = embed @ w_ih1^T + biases
// rows r = t*32 + b, M=4096, N=2048, K=256
__global__ __launch_bounds__(256) void k_xw1(const int* __restrict__ gt,
    const float* __restrict__ emb, const float* __restrict__ w_ih1,
    const float* __restrict__ b_ih1, const float* __restrict__ b_hh1,
    float* __restrict__ xW1)
{
  const int wave = (blockIdx.x << 2) + (threadIdx.x >> 6);
  const int lane = threadIdx.x & 63, l15 = lane & 15, lg = lane >> 4;
  const int mt = wave >> 5, n0 = (wave & 31) * 64;
  const int r = mt * 16 + l15;
  const int tt = r >> 5, bb = r & 31;
  const int tok = (tt == 0) ? 0 : gt[bb * L_ + tt - 1];
  const float* arow = emb + (size_t)tok * E_ + lg * 8;

  f32x4 acc[4] = {};
  for (int kt = 0; kt < 8; ++kt){
    short8 af = ld8f_bf(arow + kt * 32);
    #pragma unroll
    for (int g = 0; g < 4; ++g){
      const int j = n0 + g * 16 + l15;
      short8 bw = ld8f_bf(w_ih1 + (size_t)j * E_ + kt * 32 + lg * 8);
      acc[g] = mfma16(af, bw, acc[g]);
    }
  }
  #pragma unroll
  for (int g = 0; g < 4; ++g){
    const int j = n0 + g * 16 + l15;
    const float bias = b_ih1[j] + b_hh1[j];
    const int rr = mt * 16 + lg * 4;
    #pragma unroll
    for (int reg = 0; reg < 4; ++reg)
      xW1[(size_t)(rr + reg) * G4 + j] = acc[g][reg] + bias;
  }
}

// -------------------------------------------------- one timestep (fused)
// blocks 0..31 : layer1 step t      (needs h1[t-1])          [skip if t==128]
// blocks 32..63: layer2 step t-1    (needs h1[t-1], h2[t-2]) [skip if t==0]
__global__ __launch_bounds__(256) void k_step(int t,
    const float* __restrict__ xW1,
    const short* __restrict__ wb1, const short* __restrict__ wb2,
    const short* __restrict__ wb3,
    const float* __restrict__ b_ih2, const float* __restrict__ b_hh2,
    short* __restrict__ h1b, float* __restrict__ c1, float* __restrict__ c2,
    short* __restrict__ h2all)
{
  __shared__ f32x4 red[3 * 512];
  const int bid = blockIdx.x;
  const int w = threadIdx.x >> 6;
  const int lane = threadIdx.x & 63;
  const int l15 = lane & 15, lg = lane >> 4;

  f32x4 acc[4][2] = {};
  const bool is_l1 = (bid < 32);

  if (is_l1){
    if (t >= L_) return;
    const int u0 = bid * 16;
    const short* h1r = h1b + (size_t)(t & 1) * (B_ * H_);
    const int kbase = w * 128;
    #pragma unroll
    for (int ki = 0; ki < 4; ++ki){
      const int k0 = kbase + ki * 32 + lg * 8;
      short8 a0 = *(const short8*)(h1r + (size_t)l15 * H_ + k0);
      short8 a1 = *(const short8*)(h1r + (size_t)(l15 + 16) * H_ + k0);
      #pragma unroll
      for (int g = 0; g < 4; ++g){
        short8 bw = *(const short8*)(wb1 + (size_t)(g * H_ + u0 + l15) * H_ + k0);
        acc[g][0] = mfma16(a0, bw, acc[g][0]);
        acc[g][1] = mfma16(a1, bw, acc[g][1]);
      }
    }
  } else {
    if (t < 1) return;
    const int s = t - 1;
    const int u0 = (bid - 32) * 16;
    const short* A = nullptr; const short* W = nullptr;
    if (w < 2){ A = h1b + (size_t)(t & 1) * (B_ * H_); W = wb2; }
    else if (s >= 1){ A = h2all + (size_t)(s - 1) * (B_ * H_); W = wb3; }
    if (A){
      const int kbase = (w & 1) * 256;
      #pragma unroll
      for (int ki = 0; ki < 8; ++ki){
        const int k0 = kbase + ki * 32 + lg * 8;
        short8 a0 = *(const short8*)(A + (size_t)l15 * H_ + k0);
        short8 a1 = *(const short8*)(A + (size_t)(l15 + 16) * H_ + k0);
        #pragma unroll
        for (int g = 0; g < 4; ++g){
          short8 bw = *(const short8*)(W + (size_t)(g * H_ + u0 + l15) * H_ + k0);
          acc[g][0] = mfma16(a0, bw, acc[g][0]);
          acc[g][1] = mfma16(a1, bw, acc[g][1]);
        }
      }
    }
  }

  if (w > 0){
    #pragma unroll
    for (int g = 0; g < 4; ++g)
      #pragma unroll
      for (int mt = 0; mt < 2; ++mt)
        red[(w - 1) * 512 + (g * 2 + mt) * 64 + lane] = acc[g][mt];
  }
  __syncthreads();
  if (w != 0) return;
  #pragma unroll
  for (int g = 0; g < 4; ++g)
    #pragma unroll
    for (int mt = 0; mt < 2; ++mt){
      f32x4 v = acc[g][mt];
      v += red[0 * 512 + (g * 2 + mt) * 64 + lane];
      v += red[1 * 512 + (g * 2 + mt) * 64 + lane];
      v += red[2 * 512 + (g * 2 + mt) * 64 + lane];
      acc[g][mt] = v;
    }

  if (is_l1){
    const int u = bid * 16 + l15;
    #pragma unroll
    for (int mt = 0; mt < 2; ++mt)
      #pragma unroll
      for (int reg = 0; reg < 4; ++reg){
        const int bb = mt * 16 + lg * 4 + reg;
        const float* xr = xW1 + (size_t)(t * B_ + bb) * G4;
        float gi = acc[0][mt][reg] + xr[0 * H_ + u];
        float gf = acc[1][mt][reg] + xr[1 * H_ + u];
        float gg = acc[2][mt][reg] + xr[2 * H_ + u];
        float go = acc[3][mt][reg] + xr[3 * H_ + u];
        float co = c1[bb * H_ + u];
        float cn = sigm(gf) * co + sigm(gi) * tanh_f(gg);
        float h  = sigm(go) * tanh_f(cn);
        c1[bb * H_ + u] = cn;
        h1b[(size_t)((t + 1) & 1) * (B_ * H_) + bb * H_ + u] = f2bf(h);
      }
  } else {
    const int s = t - 1;
    const int u = (bid - 32) * 16 + l15;
    float bias[4];
    #pragma unroll
    for (int g = 0; g < 4; ++g) bias[g] = b_ih2[g * H_ + u] + b_hh2[g * H_ + u];
    #pragma unroll
    for (int mt = 0; mt < 2; ++mt)
      #pragma unroll
      for (int reg = 0; reg < 4; ++reg){
        const int bb = mt * 16 + lg * 4 + reg;
        float gi = acc[0][mt][reg] + bias[0];
        float gf = acc[1][mt][reg] + bias[1];
        float gg = acc[2][mt][reg] + bias[2];
        float go = acc[3][mt][reg] + bias[3];
        float co = c2[bb * H_ + u];
        float cn = sigm(gf) * co + sigm(gi) * tanh_f(gg);
        float h  = sigm(go) * tanh_f(cn);
        c2[bb * H_ + u] = cn;
        h2all[(size_t)(s * B_ + bb) * H_ + u] = f2bf(h);
      }
  }
}

// ----------------------------- logits = h2_all @ w_out^T + b_out, + expsum
// grid (32 mtiles, 250 ntiles); 128x128 tile, BK=32, bf16 MFMA
__global__ __launch_bounds__(256) void k_gemm_out(
    const short* __restrict__ h2all, const float* __restrict__ w_out,
    const float* __restrict__ b_out, float* __restrict__ out,
    float* __restrict__ row_sum)
{
  __shared__ __align__(16) short As[128 * 40];   // row stride 80B: conflict-free-ish
  __shared__ __align__(16) short Bs[128 * 40];
  const int r0 = blockIdx.x * 128, n0 = blockIdx.y * 128;
  const int tid = threadIdx.x;
  const int w = tid >> 6, lane = tid & 63, l15 = lane & 15, lg = lane >> 4;
  const int mrow0 = (w >> 1) * 64, ncol0 = (w & 1) * 64;

  f32x4 acc[4][4] = {};

  for (int kt = 0; kt < 16; ++kt){
    const int kg = kt * 32;
    #pragma unroll
    for (int ss = 0; ss < 2; ++ss){
      const int slot = tid + ss * 256;
      const int row = slot >> 2, k8 = (slot & 3) * 8;
      *(short8*)(As + row * 40 + k8) =
          *(const short8*)(h2all + (size_t)(r0 + row) * H_ + kg + k8);
      *(short8*)(Bs + row * 40 + k8) =
          ld8f_bf(w_out + (size_t)(n0 + row) * H_ + kg + k8);
    }
    __syncthreads();
    short8 af[4], bfr[4];
    #pragma unroll
    for (int i = 0; i < 4; ++i){
      af[i]  = *(const short8*)(As + (mrow0 + i * 16 + l15) * 40 + lg * 8);
      bfr[i] = *(const short8*)(Bs + (ncol0 + i * 16 + l15) * 40 + lg * 8);
    }
    #pragma unroll
    for (int mi = 0; mi < 4; ++mi)
      #pragma unroll
      for (int nj = 0; nj < 4; ++nj)
        acc[mi][nj] = mfma16(af[mi], bfr[nj], acc[mi][nj]);
    __syncthreads();
  }

  float bo[4];
  #pragma unroll
  for (int nj = 0; nj < 4; ++nj) bo[nj] = b_out[n0 + ncol0 + nj * 16 + l15];

  #pragma unroll
  for (int mi = 0; mi < 4; ++mi){
    #pragma unroll
    for (int reg = 0; reg < 4; ++reg){
      const int r = r0 + mrow0 + mi * 16 + lg * 4 + reg;   // = t*32 + b
      const int tt = r >> 5, bb = r & 31;
      float* orow = out + ((size_t)bb * L_ + tt) * V_;
      float esum = 0.f;
      #pragma unroll
      for (int nj = 0; nj < 4; ++nj){
        float logit = acc[mi][nj][reg] + bo[nj];
        orow[n0 + ncol0 + nj * 16 + l15] = logit;
        esum += __expf(logit);
      }
      esum += __shfl_xor(esum, 1);
      esum += __shfl_xor(esum, 2);
      esum += __shfl_xor(esum, 4);
      esum += __shfl_xor(esum, 8);
      if (l15 == 0) atomicAdd(&row_sum[r], esum);
    }
  }
}

__global__ void k_lse(float* row_sum){
  int i = blockIdx.x * blockDim.x + threadIdx.x;
  if (i < B_ * L_) row_sum[i] = __logf(row_sum[i]);
}

__global__ void k_fix(float* __restrict__ out, const float* __restrict__ lse){
  const size_t stride = (size_t)gridDim.x * blockDim.x;
  const size_t nvec = (size_t)B_ * L_ * V_ / 4;
  for (size_t i = (size_t)blockIdx.x * blockDim.x + threadIdx.x; i < nvec; i += stride){
    const int orow = (int)(i / (V_ / 4));         // = b*128 + t
    const int tt = orow & (L_ - 1), bb = orow >> 7;
    const float l = lse[tt * B_ + bb];
    f32x4 v = ((const f32x4*)out)[i];
    v[0] -= l; v[1] -= l; v[2] -= l; v[3] -= l;
    ((f32x4*)out)[i] = v;
  }
}

// ---------------------------------------------------------------- host
extern "C" void kernel_launch(void* const* d_in, const int* in_sizes, int n_in,
                              void* d_out, int out_size, void* d_ws, size_t ws_size,
                              hipStream_t stream)
{
  (void)in_sizes; (void)n_in; (void)out_size;
  const float* cnn   = (const float*)d_in[0];
  const float* emb   = (const float*)d_in[1];
  const float* w_ih1 = (const float*)d_in[2];
  const float* w_hh1 = (const float*)d_in[3];
  const float* b_ih1 = (const float*)d_in[4];
  const float* b_hh1 = (const float*)d_in[5];
  const float* w_ih2 = (const float*)d_in[6];
  const float* w_hh2 = (const float*)d_in[7];
  const float* b_ih2 = (const float*)d_in[8];
  const float* b_hh2 = (const float*)d_in[9];
  const float* w_out = (const float*)d_in[10];
  const float* b_out = (const float*)d_in[11];
  const int*   gt    = (const int*)d_in[12];
  float* out = (float*)d_out;

  char* p = (char*)d_ws;
  size_t off = 0;
  auto carve = [&](size_t bytes)->char* {
    char* q = p + off; off = (off + bytes + 255) & ~(size_t)255; return q;
  };
  short* wb1     = (short*)carve(2097152);   // w_hh1 bf16
  short* wb2     = (short*)carve(2097152);   // w_ih2 bf16
  short* wb3     = (short*)carve(2097152);   // w_hh2 bf16
  short* h2all   = (short*)carve(4194304);   // (L*B, H) bf16
  short* h1b     = (short*)carve(65536);     // double-buffered h1, bf16
  float* c1      = (float*)carve(65536);
  float* c2      = (float*)carve(65536);
  float* row_sum = (float*)carve(16384);
  float* xW1;
  if (ws_size >= off + 33554432ull + 256ull){
    xW1 = (float*)carve(33554432);
  } else {
    // xW1 is fully consumed by the step kernels before k_gemm_out first
    // writes d_out (sequential stream), so d_out is safe scratch for it.
    xW1 = out;
  }

  hipLaunchKernelGGL(k_init, dim3(1024), dim3(256), 0, stream,
                     cnn, w_hh1, w_ih2, w_hh2, wb1, wb2, wb3, c1, c2, h1b, row_sum);
  hipLaunchKernelGGL(k_xw1, dim3(2048), dim3(256), 0, stream,
                     gt, emb, w_ih1, b_ih1, b_hh1, xW1);
  for (int t = 0; t <= L_; ++t)
    hipLaunchKernelGGL(k_step, dim3(64), dim3(256), 0, stream,
                       t, xW1, wb1, wb2, wb3, b_ih2, b_hh2, h1b, c1, c2, h2all);
  hipLaunchKernelGGL(k_gemm_out, dim3(32, 250), dim3(256), 0, stream,
                     h2all, w_out, b_out, out, row_sum);
  hipLaunchKernelGGL(k_lse, dim3(16), dim3(256), 0, stream, row_sum);
  hipLaunchKernelGGL(k_fix, dim3(2048), dim3(256), 0, stream, out, row_sum);
}